// Round 3
// baseline (510.387 us; speedup 1.0000x reference)
//
#include <hip/hip_runtime.h>
#include <stdint.h>

typedef int int32x4  __attribute__((ext_vector_type(4)));
typedef int int32x16 __attribute__((ext_vector_type(16)));

#define M_ROWS 8192
#define K_DIM  4096
#define N_DIM  4096

#define GPTR(p) ((const __attribute__((address_space(1))) unsigned int*)(p))
#define LPTR(p) ((__attribute__((address_space(3))) unsigned int*)(p))

// ---------- shared helper: block-wide absmax over 256 threads ----------
__device__ __forceinline__ float block_absmax_256(float v, float* red) {
#pragma unroll
  for (int off = 32; off > 0; off >>= 1)
    v = fmaxf(v, __shfl_down(v, off, 64));
  const int w = threadIdx.x >> 6;
  if ((threadIdx.x & 63) == 0) red[w] = v;
  __syncthreads();
  return fmaxf(fmaxf(red[0], red[1]), fmaxf(red[2], red[3]));
}

// ---------- 1. per-row quantize x -> int8 + scale (lane-contiguous loads) ----------
__global__ void quant_x_kernel(const float* __restrict__ x,
                               int8_t* __restrict__ qx,
                               float* __restrict__ sx) {
  __shared__ float red[4];
  const int row = blockIdx.x;
  const int t = threadIdx.x;
  const float* xr = x + (size_t)row * K_DIM;
  float4 v[4];
  float m = 0.0f;
#pragma unroll
  for (int i = 0; i < 4; ++i) {
    v[i] = *(const float4*)(xr + i * 1024 + t * 4);  // wave: 1 KiB contiguous
    m = fmaxf(m, fmaxf(fmaxf(fabsf(v[i].x), fabsf(v[i].y)),
                       fmaxf(fabsf(v[i].z), fabsf(v[i].w))));
  }
  float amax = block_absmax_256(m, red);
  float scale = amax / 127.0f;
  if (scale == 0.0f) scale = 1.0f;
  if (t == 0) sx[row] = scale;
#pragma unroll
  for (int i = 0; i < 4; ++i) {
    float a = fminf(fmaxf(v[i].x / scale, -127.0f), 127.0f);
    float b = fminf(fmaxf(v[i].y / scale, -127.0f), 127.0f);
    float c = fminf(fmaxf(v[i].z / scale, -127.0f), 127.0f);
    float d = fminf(fmaxf(v[i].w / scale, -127.0f), 127.0f);
    int qa = (int)rintf(a), qb = (int)rintf(b), qc = (int)rintf(c), qd = (int)rintf(d);
    int word = (qa & 255) | ((qb & 255) << 8) | ((qc & 255) << 16) | ((qd & 255) << 24);
    *(int*)(qx + (size_t)row * K_DIM + i * 1024 + t * 4) = word;
  }
}

// ---------- 2. per-column partial absmax of kernel (no atomics) ----------
__global__ void colmax_kernel(const float* __restrict__ k,
                              float* __restrict__ pm) {
  const int c = blockIdx.x * 256 + threadIdx.x;
  const int r0 = blockIdx.y * 128;
  float m = 0.0f;
  for (int i = 0; i < 128; ++i)
    m = fmaxf(m, fabsf(k[(size_t)(r0 + i) * N_DIM + c]));
  pm[(size_t)blockIdx.y * N_DIM + c] = m;
}

// ---------- 3. finalize: reduce partials -> s_k; bias int16 fake-quant ----------
__global__ void finalize_kernel(const float* __restrict__ pm,
                                float* __restrict__ sk,
                                const float* __restrict__ bias,
                                float* __restrict__ bq) {
  __shared__ float red[4];
  const int t = threadIdx.x;
  if (blockIdx.x < 16) {
    const int c = blockIdx.x * 256 + t;
    float m = 0.0f;
#pragma unroll
    for (int i = 0; i < 32; ++i) m = fmaxf(m, pm[(size_t)i * N_DIM + c]);
    float s = m / 127.0f;
    if (s == 0.0f) s = 1.0f;
    sk[c] = s;
  } else {
    float4 v[4];
    float m = 0.0f;
#pragma unroll
    for (int i = 0; i < 4; ++i) {
      v[i] = *(const float4*)(bias + i * 1024 + t * 4);
      m = fmaxf(m, fmaxf(fmaxf(fabsf(v[i].x), fabsf(v[i].y)),
                         fmaxf(fabsf(v[i].z), fabsf(v[i].w))));
    }
    float amax = block_absmax_256(m, red);
    float s = amax / 32767.0f;
    if (s == 0.0f) s = 1.0f;
#pragma unroll
    for (int i = 0; i < 4; ++i) {
      float4 o;
      o.x = rintf(fminf(fmaxf(v[i].x / s, -32767.0f), 32767.0f)) * s;
      o.y = rintf(fminf(fmaxf(v[i].y / s, -32767.0f), 32767.0f)) * s;
      o.z = rintf(fminf(fmaxf(v[i].z / s, -32767.0f), 32767.0f)) * s;
      o.w = rintf(fminf(fmaxf(v[i].w / s, -32767.0f), 32767.0f)) * s;
      *(float4*)(bq + i * 1024 + t * 4) = o;
    }
  }
}

// ---------- 4. quantize kernel per-col and transpose -> qkT[F][D] int8 ----------
__global__ void quant_kT_kernel(const float* __restrict__ kern,
                                const float* __restrict__ sk,
                                int8_t* __restrict__ qkT) {
  __shared__ int8_t tile[64][80];
  const int t = threadIdx.x;
  const int c0 = blockIdx.x * 64;
  const int r0 = blockIdx.y * 64;
  const int colg = (t & 15) * 4;
  const int row = t >> 4;
  float s[4];
#pragma unroll
  for (int j = 0; j < 4; ++j) s[j] = sk[c0 + colg + j];  // already finalized scale
#pragma unroll
  for (int i = 0; i < 4; ++i) {
    const int r = row + i * 16;
    float4 v = *(const float4*)&kern[(size_t)(r0 + r) * N_DIM + c0 + colg];
    tile[colg + 0][r] = (int8_t)rintf(fminf(fmaxf(v.x / s[0], -127.0f), 127.0f));
    tile[colg + 1][r] = (int8_t)rintf(fminf(fmaxf(v.y / s[1], -127.0f), 127.0f));
    tile[colg + 2][r] = (int8_t)rintf(fminf(fmaxf(v.z / s[2], -127.0f), 127.0f));
    tile[colg + 3][r] = (int8_t)rintf(fminf(fmaxf(v.w / s[3], -127.0f), 127.0f));
  }
  __syncthreads();
  const int f = t >> 2;
  const int seg = (t & 3) * 16;
  int4 w = *(const int4*)&tile[f][seg];
  *(int4*)(qkT + (size_t)(c0 + f) * K_DIM + r0 + seg) = w;
}

// ---------- 5. int8 GEMM: 32x32x32 MFMA, BK=128, XCD-slab swizzle ----------
#define BM 128
#define BN 128
#define BK 128

__global__ void gemm_kernel(const int8_t* __restrict__ qx,
                            const int8_t* __restrict__ qkT,
                            const float* __restrict__ sx,
                            const float* __restrict__ sk,
                            const float* __restrict__ bq,
                            float* __restrict__ out) {
  __shared__ int32x4 AsV[1024];  // 16 KiB: A tile [128 rows][128 bytes]
  __shared__ int32x4 BsV[1024];  // 16 KiB: B tile [128 cols][128 bytes]
  char* As = (char*)AsV;
  char* Bs = (char*)BsV;

  const int t = threadIdx.x;
  const int w = t >> 6;
  const int l = t & 63;
  const int wm = w >> 1, wn = w & 1;

  // XCD slab swizzle: id%8 ~ XCD (round-robin heuristic). Each XCD owns a
  // 4-col-tile slab (512 cols x 4096 K = 2 MiB of qkT -> fits 4 MiB L2);
  // qx (32 MiB) streams via LLC.
  const int id = blockIdx.x;           // 0..2047
  const int xcd = id & 7;
  const int seq = id >> 3;             // 0..255
  const int rowBase = (seq & 63) * BM;
  const int colBase = (xcd * 4 + (seq >> 6)) * BN;

  // XOR swizzle: global k-chunk g lives at LDS slot g ^ (row & 7).
  // Staging: lane l writes LDS base + l*16 -> row l>>3, slot l&7
  //   -> fetch global chunk (l&7)^(l>>3).
  const int8_t* gA = qx  + (size_t)(rowBase + (l >> 3)) * K_DIM
                         + (((l & 7) ^ (l >> 3)) * 16);
  const int8_t* gB = qkT + (size_t)(colBase + (l >> 3)) * K_DIM
                         + (((l & 7) ^ (l >> 3)) * 16);

  // 32x32 frag rows: base + (l&31); bases are multiples of 32 so row&7 == l&7.
  int arow[2], brow[2], soff[4];
#pragma unroll
  for (int mt = 0; mt < 2; ++mt)
    arow[mt] = (wm * 64 + mt * 32 + (l & 31)) * 128;
#pragma unroll
  for (int nt = 0; nt < 2; ++nt)
    brow[nt] = (wn * 64 + nt * 32 + (l & 31)) * 128;
#pragma unroll
  for (int s = 0; s < 4; ++s)
    soff[s] = ((s * 2 + (l >> 5)) ^ (l & 7)) * 16;

  int32x16 acc[2][2];
#pragma unroll
  for (int mt = 0; mt < 2; ++mt)
#pragma unroll
    for (int nt = 0; nt < 2; ++nt)
#pragma unroll
      for (int r = 0; r < 16; ++r) acc[mt][nt][r] = 0;

  for (int k0 = 0; k0 < K_DIM; k0 += BK) {
    __syncthreads();  // previous iter's LDS reads done
#pragma unroll
    for (int j = 0; j < 4; ++j) {
      const int ca = j * 4 + w;  // 16 chunks of 8 rows x 128 B
      __builtin_amdgcn_global_load_lds(
          GPTR(gA + (size_t)ca * 8 * K_DIM + k0),
          LPTR(As + ca * 1024), 16, 0, 0);
      __builtin_amdgcn_global_load_lds(
          GPTR(gB + (size_t)ca * 8 * K_DIM + k0),
          LPTR(Bs + ca * 1024), 16, 0, 0);
    }
    __syncthreads();  // drain vmcnt(0) before reads

#pragma unroll
    for (int s = 0; s < 4; ++s) {  // K-steps of 32
      int32x4 af[2], bf[2];
#pragma unroll
      for (int mt = 0; mt < 2; ++mt)
        af[mt] = *(const int32x4*)(As + arow[mt] + soff[s]);
#pragma unroll
      for (int nt = 0; nt < 2; ++nt)
        bf[nt] = *(const int32x4*)(Bs + brow[nt] + soff[s]);
#pragma unroll
      for (int mt = 0; mt < 2; ++mt)
#pragma unroll
        for (int nt = 0; nt < 2; ++nt)
          acc[mt][nt] = __builtin_amdgcn_mfma_i32_32x32x32_i8(
              af[mt], bf[nt], acc[mt][nt], 0, 0, 0);
    }
  }

  // epilogue: y = acc * sx[row] * sk[col] + bq[col]
  // 32x32 C/D layout: col = l&31, row = (reg&3) + 8*(reg>>2) + 4*(l>>5)
  const int l5 = (l >> 5) * 4;
  const int lc = l & 31;
#pragma unroll
  for (int mt = 0; mt < 2; ++mt) {
    const int rbase = rowBase + wm * 64 + mt * 32;
    float sxr[16];
#pragma unroll
    for (int reg = 0; reg < 16; ++reg)
      sxr[reg] = sx[rbase + (reg & 3) + 8 * (reg >> 2) + l5];
#pragma unroll
    for (int nt = 0; nt < 2; ++nt) {
      const int c = colBase + wn * 64 + nt * 32 + lc;
      const float skc = sk[c];
      const float bqc = bq[c];
#pragma unroll
      for (int reg = 0; reg < 16; ++reg) {
        const int r = rbase + (reg & 3) + 8 * (reg >> 2) + l5;
        out[(size_t)r * N_DIM + c] =
            (float)acc[mt][nt][reg] * (sxr[reg] * skc) + bqc;
      }
    }
  }
}

// ---------- 6. per-row int8 requant of output (in place) ----------
__global__ void requant_kernel(float* __restrict__ y) {
  __shared__ float red[4];
  const int row = blockIdx.x;
  const int t = threadIdx.x;
  float* yr = y + (size_t)row * N_DIM;
  float4 v[4];
  float m = 0.0f;
#pragma unroll
  for (int i = 0; i < 4; ++i) {
    v[i] = *(const float4*)(yr + i * 1024 + t * 4);
    m = fmaxf(m, fmaxf(fmaxf(fabsf(v[i].x), fabsf(v[i].y)),
                       fmaxf(fabsf(v[i].z), fabsf(v[i].w))));
  }
  float amax = block_absmax_256(m, red);
  float s = amax / 127.0f;
  if (s == 0.0f) s = 1.0f;
#pragma unroll
  for (int i = 0; i < 4; ++i) {
    float4 o;
    o.x = rintf(fminf(fmaxf(v[i].x / s, -127.0f), 127.0f)) * s;
    o.y = rintf(fminf(fmaxf(v[i].y / s, -127.0f), 127.0f)) * s;
    o.z = rintf(fminf(fmaxf(v[i].z / s, -127.0f), 127.0f)) * s;
    o.w = rintf(fminf(fmaxf(v[i].w / s, -127.0f), 127.0f)) * s;
    *(float4*)(yr + i * 1024 + t * 4) = o;
  }
}

extern "C" void kernel_launch(void* const* d_in, const int* in_sizes, int n_in,
                              void* d_out, int out_size, void* d_ws, size_t ws_size,
                              hipStream_t stream) {
  (void)in_sizes; (void)n_in; (void)out_size; (void)ws_size;
  const float* x    = (const float*)d_in[0];
  const float* kern = (const float*)d_in[1];
  const float* bias = (const float*)d_in[2];
  float* out = (float*)d_out;

  char* w8 = (char*)d_ws;
  int8_t* qx  = (int8_t*)w8;                       // 32 MiB
  int8_t* qkT = (int8_t*)(w8 + 33554432);          // 16 MiB
  float* sx   = (float*)(w8 + 50331648);           // 8192 f
  float* sk   = (float*)(w8 + 50331648 + 49152);   // 4096 f
  float* bq   = (float*)(w8 + 50331648 + 65536);   // 4096 f
  float* pm   = (float*)(w8 + 50331648 + 131072);  // 32*4096 f partial colmax

  quant_x_kernel<<<M_ROWS, 256, 0, stream>>>(x, qx, sx);
  colmax_kernel<<<dim3(16, 32), 256, 0, stream>>>(kern, pm);
  finalize_kernel<<<17, 256, 0, stream>>>(pm, sk, bias, bq);
  quant_kT_kernel<<<dim3(64, 64), 256, 0, stream>>>(kern, sk, qkT);
  gemm_kernel<<<2048, 256, 0, stream>>>(qx, qkT, sx, sk, bq, out);
  requant_kernel<<<M_ROWS, 256, 0, stream>>>(out);
}

// Round 4
// 478.759 us; speedup vs baseline: 1.0661x; 1.0661x over previous
//
#include <hip/hip_runtime.h>
#include <stdint.h>

typedef int int32x4 __attribute__((ext_vector_type(4)));

#define M_ROWS 8192
#define K_DIM  4096
#define N_DIM  4096

#define GPTR(p) ((const __attribute__((address_space(1))) unsigned int*)(p))
#define LPTR(p) ((__attribute__((address_space(3))) unsigned int*)(p))

// ---------- shared helper: block-wide absmax over 256 threads ----------
__device__ __forceinline__ float block_absmax_256(float v, float* red) {
#pragma unroll
  for (int off = 32; off > 0; off >>= 1)
    v = fmaxf(v, __shfl_down(v, off, 64));
  const int w = threadIdx.x >> 6;
  if ((threadIdx.x & 63) == 0) red[w] = v;
  __syncthreads();
  return fmaxf(fmaxf(red[0], red[1]), fmaxf(red[2], red[3]));
}

// ---------- 1. fused prep: quant_x (blocks 0..8191) | colmax partials
//             (blocks 8192..8703) | bias int16 fake-quant (block 8704) ----------
__global__ void prep_kernel(const float* __restrict__ x,
                            const float* __restrict__ kern,
                            const float* __restrict__ bias,
                            int8_t* __restrict__ qx,
                            float* __restrict__ sx,
                            float* __restrict__ pm,
                            float* __restrict__ bq) {
  __shared__ float red[4];
  const int t = threadIdx.x;
  const int b = blockIdx.x;

  if (b < M_ROWS) {
    // per-row quantize x -> int8 + scale
    const float* xr = x + (size_t)b * K_DIM;
    float4 v[4];
    float m = 0.0f;
#pragma unroll
    for (int i = 0; i < 4; ++i) {
      v[i] = *(const float4*)(xr + i * 1024 + t * 4);
      m = fmaxf(m, fmaxf(fmaxf(fabsf(v[i].x), fabsf(v[i].y)),
                         fmaxf(fabsf(v[i].z), fabsf(v[i].w))));
    }
    float amax = block_absmax_256(m, red);
    float scale = amax / 127.0f;
    if (scale == 0.0f) scale = 1.0f;
    if (t == 0) sx[b] = scale;
#pragma unroll
    for (int i = 0; i < 4; ++i) {
      float a = fminf(fmaxf(v[i].x / scale, -127.0f), 127.0f);
      float bb = fminf(fmaxf(v[i].y / scale, -127.0f), 127.0f);
      float c = fminf(fmaxf(v[i].z / scale, -127.0f), 127.0f);
      float d = fminf(fmaxf(v[i].w / scale, -127.0f), 127.0f);
      int qa = (int)rintf(a), qb = (int)rintf(bb), qc = (int)rintf(c), qd = (int)rintf(d);
      int word = (qa & 255) | ((qb & 255) << 8) | ((qc & 255) << 16) | ((qd & 255) << 24);
      *(int*)(qx + (size_t)b * K_DIM + i * 1024 + t * 4) = word;
    }
  } else if (b < M_ROWS + 512) {
    // partial per-column absmax of kern: 16 col-groups x 32 row-strips
    const int bb = b - M_ROWS;
    const int c = (bb & 15) * 256 + t;
    const int r0 = (bb >> 4) * 128;
    float m = 0.0f;
    for (int i = 0; i < 128; ++i)
      m = fmaxf(m, fabsf(kern[(size_t)(r0 + i) * N_DIM + c]));
    pm[(size_t)(bb >> 4) * N_DIM + c] = m;
  } else {
    // bias int16 fake-quant (one block)
    float4 v[4];
    float m = 0.0f;
#pragma unroll
    for (int i = 0; i < 4; ++i) {
      v[i] = *(const float4*)(bias + i * 1024 + t * 4);
      m = fmaxf(m, fmaxf(fmaxf(fabsf(v[i].x), fabsf(v[i].y)),
                         fmaxf(fabsf(v[i].z), fabsf(v[i].w))));
    }
    float amax = block_absmax_256(m, red);
    float s = amax / 32767.0f;
    if (s == 0.0f) s = 1.0f;
#pragma unroll
    for (int i = 0; i < 4; ++i) {
      float4 o;
      o.x = rintf(fminf(fmaxf(v[i].x / s, -32767.0f), 32767.0f)) * s;
      o.y = rintf(fminf(fmaxf(v[i].y / s, -32767.0f), 32767.0f)) * s;
      o.z = rintf(fminf(fmaxf(v[i].z / s, -32767.0f), 32767.0f)) * s;
      o.w = rintf(fminf(fmaxf(v[i].w / s, -32767.0f), 32767.0f)) * s;
      *(float4*)(bq + i * 1024 + t * 4) = o;
    }
  }
}

// ---------- 2. quantize kernel per-col and transpose -> qkT[F][D] int8
//             (sk computed inline from pm partials; block row 0 publishes sk) ----------
__global__ void quant_kT_kernel(const float* __restrict__ kern,
                                const float* __restrict__ pm,
                                float* __restrict__ sk,
                                int8_t* __restrict__ qkT) {
  __shared__ int8_t tile[64][80];
  __shared__ float skl[64];
  const int t = threadIdx.x;
  const int c0 = blockIdx.x * 64;
  const int r0 = blockIdx.y * 64;
  if (t < 64) {
    float m = 0.0f;
#pragma unroll
    for (int i = 0; i < 32; ++i) m = fmaxf(m, pm[(size_t)i * N_DIM + c0 + t]);
    float s = m / 127.0f;
    if (s == 0.0f) s = 1.0f;
    skl[t] = s;
    if (blockIdx.y == 0) sk[c0 + t] = s;
  }
  __syncthreads();
  const int colg = (t & 15) * 4;
  const int row = t >> 4;
  float s[4];
#pragma unroll
  for (int j = 0; j < 4; ++j) s[j] = skl[colg + j];
#pragma unroll
  for (int i = 0; i < 4; ++i) {
    const int r = row + i * 16;
    float4 v = *(const float4*)&kern[(size_t)(r0 + r) * N_DIM + c0 + colg];
    tile[colg + 0][r] = (int8_t)rintf(fminf(fmaxf(v.x / s[0], -127.0f), 127.0f));
    tile[colg + 1][r] = (int8_t)rintf(fminf(fmaxf(v.y / s[1], -127.0f), 127.0f));
    tile[colg + 2][r] = (int8_t)rintf(fminf(fmaxf(v.z / s[2], -127.0f), 127.0f));
    tile[colg + 3][r] = (int8_t)rintf(fminf(fmaxf(v.w / s[3], -127.0f), 127.0f));
  }
  __syncthreads();
  const int f = t >> 2;
  const int seg = (t & 3) * 16;
  int4 w = *(const int4*)&tile[f][seg];
  *(int4*)(qkT + (size_t)(c0 + f) * K_DIM + r0 + seg) = w;
}

// ---------- 3. int8 GEMM: R2 structure + LDS double-buffer, 1 barrier/iter ----------
// Prefetch for tile k+1 is issued AFTER the barrier, so the barrier's vmcnt(0)
// only drains the current tile's loads — which had a full compute phase in
// flight. LDS 64 KiB -> 2 blocks/CU; the bet is prefetch > TLP here.
#define BM 128
#define BN 128
#define BK 128

__global__ void gemm_kernel(const int8_t* __restrict__ qx,
                            const int8_t* __restrict__ qkT,
                            const float* __restrict__ sx,
                            const float* __restrict__ sk,
                            const float* __restrict__ bq,
                            float* __restrict__ out) {
  __shared__ int32x4 AsV[2048];  // 2 x 16 KiB
  __shared__ int32x4 BsV[2048];  // 2 x 16 KiB
  char* As = (char*)AsV;
  char* Bs = (char*)BsV;

  const int t = threadIdx.x;
  const int w = t >> 6;
  const int l = t & 63;
  const int wm = w >> 1, wn = w & 1;
  const int rowBase = blockIdx.y * BM;
  const int colBase = blockIdx.x * BN;

  // XOR swizzle (R2, measured 0 conflicts): global k-chunk g at LDS slot
  // g ^ (row & 7). Staging lane l -> row l>>3, slot l&7 -> global chunk
  // (l&7)^(l>>3).
  const int8_t* gA = qx  + (size_t)(rowBase + (l >> 3)) * K_DIM
                         + (((l & 7) ^ (l >> 3)) * 16);
  const int8_t* gB = qkT + (size_t)(colBase + (l >> 3)) * K_DIM
                         + (((l & 7) ^ (l >> 3)) * 16);

  int arow[4], brow[4], soff[2];
#pragma unroll
  for (int mt = 0; mt < 4; ++mt)
    arow[mt] = (wm * 64 + mt * 16 + (l & 15)) * 128;
#pragma unroll
  for (int nt = 0; nt < 4; ++nt)
    brow[nt] = (wn * 64 + nt * 16 + (l & 15)) * 128;
#pragma unroll
  for (int s = 0; s < 2; ++s)
    soff[s] = ((s * 4 + (l >> 4)) ^ (l & 7)) * 16;

  int32x4 zero = {0, 0, 0, 0};
  int32x4 acc[4][4];
#pragma unroll
  for (int mt = 0; mt < 4; ++mt)
#pragma unroll
    for (int nt = 0; nt < 4; ++nt) acc[mt][nt] = zero;

  // prologue: stage tile 0 into buffer 0
#pragma unroll
  for (int j = 0; j < 4; ++j) {
    const int ca = j * 4 + w;
    __builtin_amdgcn_global_load_lds(GPTR(gA + (size_t)ca * 8 * K_DIM),
                                     LPTR(As + ca * 1024), 16, 0, 0);
    __builtin_amdgcn_global_load_lds(GPTR(gB + (size_t)ca * 8 * K_DIM),
                                     LPTR(Bs + ca * 1024), 16, 0, 0);
  }

#pragma unroll 2
  for (int k0 = 0; k0 < K_DIM; k0 += BK) {
    const int p = (k0 >> 7) & 1;
    const int pb = p * 16384;
    __syncthreads();  // drains current tile's loads (issued 1 iter ago)

    if (k0 + BK < K_DIM) {
      const int qb = (p ^ 1) * 16384;
#pragma unroll
      for (int j = 0; j < 4; ++j) {
        const int ca = j * 4 + w;
        __builtin_amdgcn_global_load_lds(
            GPTR(gA + (size_t)ca * 8 * K_DIM + k0 + BK),
            LPTR(As + qb + ca * 1024), 16, 0, 0);
        __builtin_amdgcn_global_load_lds(
            GPTR(gB + (size_t)ca * 8 * K_DIM + k0 + BK),
            LPTR(Bs + qb + ca * 1024), 16, 0, 0);
      }
    }

#pragma unroll
    for (int s = 0; s < 2; ++s) {
      int32x4 af[4], bf[4];
#pragma unroll
      for (int mt = 0; mt < 4; ++mt)
        af[mt] = *(const int32x4*)(As + pb + arow[mt] + soff[s]);
#pragma unroll
      for (int nt = 0; nt < 4; ++nt)
        bf[nt] = *(const int32x4*)(Bs + pb + brow[nt] + soff[s]);
#pragma unroll
      for (int mt = 0; mt < 4; ++mt)
#pragma unroll
        for (int nt = 0; nt < 4; ++nt)
          acc[mt][nt] = __builtin_amdgcn_mfma_i32_16x16x64_i8(
              af[mt], bf[nt], acc[mt][nt], 0, 0, 0);
    }
  }

  // epilogue: y = acc * sx[row] * sk[col] + bq[col]
  const int lr = (l >> 4) * 4;
  const int lc = l & 15;
#pragma unroll
  for (int mt = 0; mt < 4; ++mt) {
    const int r0 = rowBase + wm * 64 + mt * 16 + lr;
    float sxr[4];
#pragma unroll
    for (int r = 0; r < 4; ++r) sxr[r] = sx[r0 + r];
#pragma unroll
    for (int nt = 0; nt < 4; ++nt) {
      const int c = colBase + wn * 64 + nt * 16 + lc;
      const float skc = sk[c];
      const float bqc = bq[c];
#pragma unroll
      for (int r = 0; r < 4; ++r)
        out[(size_t)(r0 + r) * N_DIM + c] =
            (float)acc[mt][nt][r] * (sxr[r] * skc) + bqc;
    }
  }
}

// ---------- 4. per-row int8 requant of output (in place) ----------
__global__ void requant_kernel(float* __restrict__ y) {
  __shared__ float red[4];
  const int row = blockIdx.x;
  const int t = threadIdx.x;
  float* yr = y + (size_t)row * N_DIM;
  float4 v[4];
  float m = 0.0f;
#pragma unroll
  for (int i = 0; i < 4; ++i) {
    v[i] = *(const float4*)(yr + i * 1024 + t * 4);
    m = fmaxf(m, fmaxf(fmaxf(fabsf(v[i].x), fabsf(v[i].y)),
                       fmaxf(fabsf(v[i].z), fabsf(v[i].w))));
  }
  float amax = block_absmax_256(m, red);
  float s = amax / 127.0f;
  if (s == 0.0f) s = 1.0f;
#pragma unroll
  for (int i = 0; i < 4; ++i) {
    float4 o;
    o.x = rintf(fminf(fmaxf(v[i].x / s, -127.0f), 127.0f)) * s;
    o.y = rintf(fminf(fmaxf(v[i].y / s, -127.0f), 127.0f)) * s;
    o.z = rintf(fminf(fmaxf(v[i].z / s, -127.0f), 127.0f)) * s;
    o.w = rintf(fminf(fmaxf(v[i].w / s, -127.0f), 127.0f)) * s;
    *(float4*)(yr + i * 1024 + t * 4) = o;
  }
}

extern "C" void kernel_launch(void* const* d_in, const int* in_sizes, int n_in,
                              void* d_out, int out_size, void* d_ws, size_t ws_size,
                              hipStream_t stream) {
  (void)in_sizes; (void)n_in; (void)out_size; (void)ws_size;
  const float* x    = (const float*)d_in[0];
  const float* kern = (const float*)d_in[1];
  const float* bias = (const float*)d_in[2];
  float* out = (float*)d_out;

  char* w8 = (char*)d_ws;
  int8_t* qx  = (int8_t*)w8;                       // 32 MiB
  int8_t* qkT = (int8_t*)(w8 + 33554432);          // 16 MiB
  float* sx   = (float*)(w8 + 50331648);           // 8192 f
  float* sk   = (float*)(w8 + 50331648 + 49152);   // 4096 f
  float* bq   = (float*)(w8 + 50331648 + 65536);   // 4096 f
  float* pm   = (float*)(w8 + 50331648 + 131072);  // 32*4096 f partial colmax

  prep_kernel<<<M_ROWS + 512 + 1, 256, 0, stream>>>(x, kern, bias, qx, sx, pm, bq);
  quant_kT_kernel<<<dim3(64, 64), 256, 0, stream>>>(kern, pm, sk, qkT);
  gemm_kernel<<<dim3(N_DIM / BN, M_ROWS / BM), 256, 0, stream>>>(qx, qkT, sx, sk, bq, out);
  requant_kernel<<<M_ROWS, 256, 0, stream>>>(out);
}